// Round 1
// baseline (110.311 us; speedup 1.0000x reference)
//
#include <hip/hip_runtime.h>

// Problem constants (fixed by the reference)
#define NB   8
#define C    128
#define H    112
#define W    112
#define HW   (H * W)
#define HO   56
#define WO   56
#define KK   9      // 3x3 = 9 sigma channels
#define WAVES 16
#define CPW  8      // channels per wave = C / WAVES
#define NPAIR (C / 2)            // 64 channel pairs
#define PPW  (CPW / 2)           // 4 pairs per wave
#define WPK_ELEMS (NPAIR * 81)   // float2 count: [cip][kh][k*3+kw]
#define SHIFT_OFF (WPK_ELEMS * 2)  // float offset of shift[9] in ws

typedef float v2f __attribute__((ext_vector_type(2)));

// ---------------------------------------------------------------------------
// Kernel 0: weights -> d_ws as channel-PAIR packed float2, BN scale folded.
// ---------------------------------------------------------------------------
__global__ void pasa_prep(const float* __restrict__ cw,
                          const float* __restrict__ bw,
                          const float* __restrict__ bb,
                          const float* __restrict__ bm,
                          const float* __restrict__ bv,
                          float* __restrict__ ws) {
    int idx = blockIdx.x * 256 + threadIdx.x;
    if (idx < WPK_ELEMS) {
        int cip = idx / 81;
        int rem = idx % 81;
        int kh = rem / 27;
        int r2 = rem % 27;
        int k  = r2 / 3;
        int kw = r2 % 3;
        float scale = bw[k] / sqrtf(bv[k] + 1e-5f);
        int ca = 2 * cip, cb = 2 * cip + 1;
        ws[2 * idx + 0] = cw[((k * C + ca) * 3 + kh) * 3 + kw] * scale;
        ws[2 * idx + 1] = cw[((k * C + cb) * 3 + kh) * 3 + kw] * scale;
    } else if (idx < WPK_ELEMS + KK) {
        int k = idx - WPK_ELEMS;
        float scale = bw[k] / sqrtf(bv[k] + 1e-5f);
        ws[SHIFT_OFF + k] = bb[k] - bm[k] * scale;
    }
}

// Packed fp32 fma -> v_pk_fma_f32 on gfx950 (VOP3P); falls back to 2x v_fma.
__device__ inline v2f pkfma(v2f a, v2f b, v2f c) {
    return __builtin_elementwise_fma(a, b, c);
}

// ---------------------------------------------------------------------------
// Kernel 1: fused PASA downsample, register-resident x, TWO output rows/block.
// Grid = 8 * 28 = 224 blocks (single scheduling round, no 448/256 tail).
// Block handles ho0=2*hb and ho1=2*hb+1: input rows 4hb-1..4hb+3 (5 rows for
// 2 outputs instead of 6 -> 17% less read traffic). Rows 4hb+2/4hb+3 are
// prefetched into temp regs during the half-0 reduce/apply so their HBM
// latency hides under compute. Phase A/B use packed v_pk_fma_f32.
// __launch_bounds__(1024, 4): 1 block/CU, VGPR cap 128 (peak ~105, no spill).
// ---------------------------------------------------------------------------
__global__ __launch_bounds__(1024, 4)
void pasa_main(const float* __restrict__ x,
               const v2f* __restrict__ wpk,
               const float* __restrict__ shift,
               float* __restrict__ out) {
    __shared__ float part[WAVES * KK * 64];   // 36 KB
    __shared__ float sig[KK * 57];            // padded row stride

    // XCD swizzle: grid 224 = 8 XCDs * 28; bid%8 = n -> same-n blocks (which
    // share seam rows 4hb+3 = 4(hb+1)-1) land on the same XCD's L2.
    const int bid  = blockIdx.x;
    const int n    = bid & 7;
    const int hb   = bid >> 3;                 // 0..27
    const int tid  = threadIdx.x;
    const int lane = tid & 63;
    const int wv   = __builtin_amdgcn_readfirstlane(tid >> 6);  // wave-uniform
    const int wo   = lane < WO ? lane : (WO - 1);               // clamp tail

    // Rows for ho0 = 2*hb: reflect top (-1 -> 1) only possible at hb==0.
    const int r0 = (hb == 0) ? 1 : (4 * hb - 1);
    const int r1 = 4 * hb;
    const int r2 = 4 * hb + 1;
    // Rows for ho1 = 2*hb+1: r2, 4hb+2, 4hb+3 (max 111, no bottom reflect).
    const int r3 = 4 * hb + 2;
    const int r4 = 4 * hb + 3;

    const float* xn = x + (size_t)n * C * HW;
    const int p0 = wv * PPW;   // first channel-pair of this wave

    // ---- Load rows for half 0 (24 v2f, one drain) -------------------------
    v2f va[PPW][3], vb[PPW][3];
#pragma unroll
    for (int p = 0; p < PPW; ++p) {
        const float* xa = xn + (size_t)(2 * (p0 + p)) * HW + 2 * wo;
        const float* xb = xa + HW;
        va[p][0] = *(const v2f*)(xa + r0 * W);
        va[p][1] = *(const v2f*)(xa + r1 * W);
        va[p][2] = *(const v2f*)(xa + r2 * W);
        vb[p][0] = *(const v2f*)(xb + r0 * W);
        vb[p][1] = *(const v2f*)(xb + r1 * W);
        vb[p][2] = *(const v2f*)(xb + r2 * W);
    }

    v2f ta[PPW][2], tb[PPW][2];   // prefetch regs for rows r3, r4
    float* on_base = out + (size_t)n * C * (HO * WO);

#pragma unroll
    for (int half = 0; half < 2; ++half) {
        // ---- Phase A: packed partial sigma over the 4 channel pairs -------
        v2f acc[KK];
#pragma unroll
        for (int k = 0; k < KK; ++k) acc[k] = (v2f){0.0f, 0.0f};

#pragma unroll
        for (int p = 0; p < PPW; ++p) {
            const v2f* wb = wpk + (p0 + p) * 81;   // wave-uniform -> s_load
#pragma unroll
            for (int kh = 0; kh < 3; ++kh) {
                v2f t1 = { va[p][kh].x, vb[p][kh].x };
                v2f t2 = { va[p][kh].y, vb[p][kh].y };
                v2f t0;
                t0.x = __shfl_up(t2.x, 1);   // lane0 keeps own = reflect(-1)=col1
                t0.y = __shfl_up(t2.y, 1);
                const v2f* wr = wb + kh * 27;
#pragma unroll
                for (int k = 0; k < KK; ++k)
                    acc[k] = pkfma(t2, wr[3 * k + 2],
                              pkfma(t1, wr[3 * k + 1],
                              pkfma(t0, wr[3 * k + 0], acc[k])));
            }
        }

#pragma unroll
        for (int k = 0; k < KK; ++k)
            part[(wv * KK + k) * 64 + lane] = acc[k].x + acc[k].y;

        // ---- Prefetch half-1 rows; latency hides under reduce + Phase B ---
        if (half == 0) {
#pragma unroll
            for (int p = 0; p < PPW; ++p) {
                const float* xa = xn + (size_t)(2 * (p0 + p)) * HW + 2 * wo;
                const float* xb = xa + HW;
                ta[p][0] = *(const v2f*)(xa + r3 * W);
                ta[p][1] = *(const v2f*)(xa + r4 * W);
                tb[p][0] = *(const v2f*)(xb + r3 * W);
                tb[p][1] = *(const v2f*)(xb + r4 * W);
            }
        }
        __syncthreads();

        // ---- Cross-wave reduce + BN shift + clamp -------------------------
        if (tid < KK * WO) {
            const int k = tid / WO;
            const int w_ = tid % WO;
            float s = 0.0f;
#pragma unroll
            for (int w2 = 0; w2 < WAVES; ++w2) s += part[(w2 * KK + k) * 64 + w_];
            s += shift[k];
            s = fmaxf(s, 1e-4f);
            sig[k * 57 + w_] = s;
        }
        __syncthreads();

        // ---- Normalize into registers (per-lane, lane = wo) ---------------
        float sg[KK];
        float tot = 0.0f;
#pragma unroll
        for (int k = 0; k < KK; ++k) { sg[k] = sig[k * 57 + wo]; tot += sg[k]; }
        const float inv = 1.0f / tot;
#pragma unroll
        for (int k = 0; k < KK; ++k) sg[k] *= inv;

        // ---- Phase B: apply adaptive filter from REGISTERS (packed) -------
        const int ho = 2 * hb + half;
        float* on = on_base + (size_t)ho * WO;
#pragma unroll
        for (int p = 0; p < PPW; ++p) {
            v2f o = (v2f){0.0f, 0.0f};
#pragma unroll
            for (int kh = 0; kh < 3; ++kh) {
                v2f t1 = { va[p][kh].x, vb[p][kh].x };
                v2f t2 = { va[p][kh].y, vb[p][kh].y };
                v2f t0;
                t0.x = __shfl_up(t2.x, 1);
                t0.y = __shfl_up(t2.y, 1);
                v2f s0 = { sg[kh * 3 + 0], sg[kh * 3 + 0] };
                v2f s1 = { sg[kh * 3 + 1], sg[kh * 3 + 1] };
                v2f s2 = { sg[kh * 3 + 2], sg[kh * 3 + 2] };
                o = pkfma(t2, s2, pkfma(t1, s1, pkfma(t0, s0, o)));
            }
            if (lane < WO) {
                const int ci = 2 * (p0 + p);
                // Output is never re-read: don't pollute L2 (seam-row reuse).
                __builtin_nontemporal_store(o.x, on + (size_t)ci * (HO * WO) + lane);
                __builtin_nontemporal_store(o.y, on + (size_t)(ci + 1) * (HO * WO) + lane);
            }
        }

        // ---- Rotate register rows for half 1: (r2, r3, r4) ----------------
        if (half == 0) {
#pragma unroll
            for (int p = 0; p < PPW; ++p) {
                va[p][0] = va[p][2]; va[p][1] = ta[p][0]; va[p][2] = ta[p][1];
                vb[p][0] = vb[p][2]; vb[p][1] = tb[p][0]; vb[p][2] = tb[p][1];
            }
        }
    }
}

extern "C" void kernel_launch(void* const* d_in, const int* in_sizes, int n_in,
                              void* d_out, int out_size, void* d_ws, size_t ws_size,
                              hipStream_t stream) {
    const float* x   = (const float*)d_in[0];
    const float* cw  = (const float*)d_in[1];
    const float* bw  = (const float*)d_in[2];
    const float* bb  = (const float*)d_in[3];
    const float* bm  = (const float*)d_in[4];
    const float* bv  = (const float*)d_in[5];
    float* ws  = (float*)d_ws;
    float* out = (float*)d_out;

    const int prep_elems = WPK_ELEMS + KK;
    pasa_prep<<<(prep_elems + 255) / 256, 256, 0, stream>>>(cw, bw, bb, bm, bv, ws);
    pasa_main<<<NB * (HO / 2), 1024, 0, stream>>>(x, (const v2f*)ws,
                                                  ws + SHIFT_OFF, out);
}